// Round 1
// baseline (142.108 us; speedup 1.0000x reference)
//
#include <hip/hip_runtime.h>
#include <stdint.h>
#include <math.h>

#define A_N 65536
#define B_N 16
#define T_N 64
#define NWAVE (A_N / 64)   // waves per image in k1 = 1024
#define EPSF 1e-6f

// ---------------------------------------------------------------------------
// Workspace layout:
//   keys     : B * NWAVE * 64 targets * u64  = 8 MiB   (per-wave best anchor key per target)
//   code     : B * A uint8                   = 1 MiB   (best_target_idx | thr<<7)
//   forced   : B * A uint8                   = 1 MiB   (forced-positive flags, memset 0)
//   partials : B * 256 blocks * 4 floats     = 64 KiB  (per-block loss partial sums)
// ---------------------------------------------------------------------------

// K1: per (image, anchor): IoU against 64 targets.
//  - per-anchor argmax (cross-mult compare, tie -> smallest t) + 0.5 threshold bit
//  - per-target argmax via rotating wave accumulator (no atomics)
__global__ __launch_bounds__(256) void k1_iou(
    const float4* __restrict__ anchors,
    const float4* __restrict__ tboxes,
    unsigned long long* __restrict__ keys,
    unsigned char* __restrict__ code)
{
    __shared__ float4 tb[T_N];
    __shared__ float  ta[T_N];
    const int b   = blockIdx.y;
    const int tid = threadIdx.x;
    if (tid < T_N) {
        float4 t = tboxes[b * T_N + tid];
        tb[tid] = t;
        ta[tid] = (t.z - t.x) * (t.w - t.y);
    }
    __syncthreads();

    const int a   = blockIdx.x * 256 + tid;
    const float4 an = anchors[a];
    const float a1 = (an.z - an.x) * (an.w - an.y);
    const int lane = tid & 63;
    const unsigned int lo = ~(unsigned int)a;   // smaller idx -> larger lo (argmax-first ties)

    unsigned long long K = 0ull;        // rotating per-target accumulator
    float b_inter = 0.f, b_ue = 0.f;    // per-anchor best (init loses to any pair via tie rule)
    int   b_t = 64;

    #pragma unroll 4
    for (int s = 0; s < 64; ++s) {
        const int t = (lane + s) & 63;
        const float4 tbx = tb[t];
        float x1 = fmaxf(an.x, tbx.x);
        float y1 = fmaxf(an.y, tbx.y);
        float x2 = fminf(an.z, tbx.z);
        float y2 = fminf(an.w, tbx.w);
        float inter = fmaxf(x2 - x1, 0.f) * fmaxf(y2 - y1, 0.f);
        float u  = a1 + ta[t] - inter;
        float ue = u + EPSF;            // union + EPS  (always > 0)

        // per-anchor argmax: inter/ue > b_inter/b_ue  <=>  inter*b_ue > b_inter*ue
        float c1 = inter * b_ue;
        float c2 = b_inter * ue;
        bool upd = (c1 > c2) || ((c1 == c2) && (t < b_t));
        if (upd) { b_inter = inter; b_ue = ue; b_t = t; }

        // per-target rotating key (exact division so global ordering matches reference)
        float iou = inter / ue;
        unsigned long long key =
            ((unsigned long long)__float_as_uint(iou) << 32) | (unsigned long long)lo;
        if (key > K) K = key;
        K = __shfl(K, (lane + 1) & 63, 64);   // rotate accumulator one lane
    }
    // after 64 rotations lane l holds the wave-best key for target l
    const int gw = blockIdx.x * 4 + (tid >> 6);            // global wave id within image
    keys[(((size_t)b * NWAVE + gw) << 6) | lane] = K;

    const bool thr = (b_inter >= 0.5f * b_ue);             // max_iou >= POS_THR
    code[(size_t)b * A_N + a] = (unsigned char)(b_t | (thr ? 128 : 0));
}

// K2: reduce per-wave keys -> global best anchor per (image, target); set forced flag.
__global__ __launch_bounds__(1024) void k2_reduce(
    const unsigned long long* __restrict__ keys,
    unsigned char* __restrict__ forced)
{
    const int b   = blockIdx.x;
    const int tid = threadIdx.x;
    const int t   = tid & 63;
    const int g   = tid >> 6;     // 0..15
    unsigned long long K = 0ull;
    for (int i = 0; i < 64; ++i) {
        const int w = g + 16 * i;
        unsigned long long k = keys[(((size_t)b * NWAVE + w) << 6) | t];
        if (k > K) K = k;
    }
    __shared__ unsigned long long sh[16][64];
    sh[g][t] = K;
    __syncthreads();
    if (tid < 64) {
        unsigned long long m = sh[0][tid];
        #pragma unroll
        for (int g2 = 1; g2 < 16; ++g2) {
            unsigned long long k = sh[g2][tid];
            if (k > m) m = k;
        }
        unsigned int a_best = ~(unsigned int)(m & 0xFFFFFFFFull);
        forced[(size_t)b * A_N + a_best] = 1;
    }
}

// K3: per-anchor losses; cls/bbox tensors only touched for positive anchors.
__global__ __launch_bounds__(256) void k3_loss(
    const float4* __restrict__ bbox,
    const float*  __restrict__ conf,
    const float4* __restrict__ cls,       // 20 floats/anchor = 5 x float4
    const float4* __restrict__ tboxes,
    const int*    __restrict__ tlabels,
    const unsigned char* __restrict__ code,
    const unsigned char* __restrict__ forced,
    float* __restrict__ partials)
{
    __shared__ float4 tb[T_N];
    __shared__ int    tl[T_N];
    const int b   = blockIdx.y;
    const int tid = threadIdx.x;
    if (tid < T_N) {
        tb[tid] = tboxes[b * T_N + tid];
        tl[tid] = tlabels[b * T_N + tid];
    }
    __syncthreads();

    const int a = blockIdx.x * 256 + tid;
    const size_t ba = (size_t)b * A_N + a;
    const unsigned char c = code[ba];
    const bool pos = (((c >> 7) | forced[ba]) != 0);
    const int  bt  = c & 63;
    const float ct = pos ? 1.f : 0.f;

    // focal BCE on conf (all anchors)
    const float p  = conf[ba];
    const float w  = pos ? (1.f - p) : p;
    const float fw = w * sqrtf(w);                              // w^1.5
    const float bce = pos ? -logf(p + EPSF) : -logf(1.f - p + EPSF);
    const float cterm = bce * fw * 0.5f;                        // alpha_factor == 0.5

    float bterm = 0.f, clterm = 0.f;
    if (pos) {
        const float4 pb = bbox[ba];
        const float4 mb = tb[bt];
        float x1 = fmaxf(pb.x, mb.x), y1 = fmaxf(pb.y, mb.y);
        float x2 = fminf(pb.z, mb.z), y2 = fminf(pb.w, mb.w);
        float inter = fmaxf(x2 - x1, 0.f) * fmaxf(y2 - y1, 0.f);
        float a1 = (pb.z - pb.x) * (pb.w - pb.y);
        float a2 = (mb.z - mb.x) * (mb.w - mb.y);
        float uni = a1 + a2 - inter;
        float iou = inter / (uni + EPSF);
        float ex1 = fminf(pb.x, mb.x), ey1 = fminf(pb.y, mb.y);
        float ex2 = fmaxf(pb.z, mb.z), ey2 = fmaxf(pb.w, mb.w);
        float enc = (ex2 - ex1) * (ey2 - ey1);
        float giou = iou - (enc - uni) / (enc + EPSF);
        float gl = 1.f - giou;
        float l1 = 0.25f * (fabsf(pb.x - mb.x) + fabsf(pb.y - mb.y) +
                            fabsf(pb.z - mb.z) + fabsf(pb.w - mb.w));
        bterm = gl + 0.5f * l1;

        const int lab = tl[bt] - 1;                 // 0..19
        const float4* cp = cls + ba * 5;
        float s = 0.f, xl = 0.f;
        #pragma unroll
        for (int q = 0; q < 5; ++q) {
            float4 v = cp[q];
            float xs[4] = {v.x, v.y, v.z, v.w};
            #pragma unroll
            for (int j = 0; j < 4; ++j) {
                float x = xs[j];
                s += fmaxf(x, 0.f) + log1pf(expf(-fabsf(x)));
                if (q * 4 + j == lab) xl = x;        // static index -> cndmask, no scratch
            }
        }
        clterm = (s - xl) * (1.f / 20.f);
    }

    // block reduction of {cterm, ct, bterm, clterm}
    float r0 = cterm, r1 = ct, r2 = bterm, r3 = clterm;
    #pragma unroll
    for (int off = 32; off; off >>= 1) {
        r0 += __shfl_down(r0, off, 64);
        r1 += __shfl_down(r1, off, 64);
        r2 += __shfl_down(r2, off, 64);
        r3 += __shfl_down(r3, off, 64);
    }
    __shared__ float red[4][4];
    const int wv = tid >> 6;
    if ((tid & 63) == 0) { red[wv][0] = r0; red[wv][1] = r1; red[wv][2] = r2; red[wv][3] = r3; }
    __syncthreads();
    if (tid < 4) {
        float v = red[0][tid] + red[1][tid] + red[2][tid] + red[3][tid];
        partials[(((size_t)b * 256) + blockIdx.x) * 4 + tid] = v;
    }
}

// K4: final per-image losses and means -> 4 outputs.
__global__ __launch_bounds__(1024) void k4_final(
    const float* __restrict__ partials, float* __restrict__ out)
{
    const int tid  = threadIdx.x;
    const int b    = tid >> 6;
    const int lane = tid & 63;
    float s0 = 0.f, s1 = 0.f, s2 = 0.f, s3 = 0.f;
    #pragma unroll
    for (int i = 0; i < 4; ++i) {
        const int blk = lane + 64 * i;
        const float* p = partials + (((size_t)b * 256) + blk) * 4;
        s0 += p[0]; s1 += p[1]; s2 += p[2]; s3 += p[3];
    }
    #pragma unroll
    for (int off = 32; off; off >>= 1) {
        s0 += __shfl_down(s0, off, 64);
        s1 += __shfl_down(s1, off, 64);
        s2 += __shfl_down(s2, off, 64);
        s3 += __shfl_down(s3, off, 64);
    }
    __shared__ float L[16][3];
    if (lane == 0) {
        float confL = s0 / (float)A_N;
        float npos  = fmaxf(s1, 1.f);
        L[b][0] = confL;
        L[b][1] = s2 / npos;
        L[b][2] = s3 / npos;
    }
    __syncthreads();
    if (tid == 0) {
        float cm = 0.f, bm = 0.f, lm = 0.f;
        #pragma unroll
        for (int i = 0; i < 16; ++i) { cm += L[i][0]; bm += L[i][1]; lm += L[i][2]; }
        cm *= (1.f / 16.f); bm *= (1.f / 16.f); lm *= (1.f / 16.f);
        out[0] = cm + bm + lm;
        out[1] = cm;
        out[2] = bm;
        out[3] = lm;
    }
}

extern "C" void kernel_launch(void* const* d_in, const int* in_sizes, int n_in,
                              void* d_out, int out_size, void* d_ws, size_t ws_size,
                              hipStream_t stream)
{
    const float4* bbox    = (const float4*)d_in[0];
    const float*  conf    = (const float*) d_in[1];
    const float4* cls     = (const float4*)d_in[2];
    const float4* anchors = (const float4*)d_in[3];
    const float4* tboxes  = (const float4*)d_in[4];
    const int*    tlabels = (const int*)   d_in[5];
    float* out = (float*)d_out;

    char* ws = (char*)d_ws;
    unsigned long long* keys   = (unsigned long long*)ws;           // 8 MiB
    unsigned char*      code   = (unsigned char*)(ws + (8u << 20)); // 1 MiB
    unsigned char*      forced = (unsigned char*)(ws + (9u << 20)); // 1 MiB
    float*              partials = (float*)(ws + (10u << 20));      // 64 KiB

    hipMemsetAsync(forced, 0, (size_t)B_N * A_N, stream);

    k1_iou   <<<dim3(A_N / 256, B_N), 256, 0, stream>>>(anchors, tboxes, keys, code);
    k2_reduce<<<B_N, 1024, 0, stream>>>(keys, forced);
    k3_loss  <<<dim3(A_N / 256, B_N), 256, 0, stream>>>(bbox, conf, cls, tboxes, tlabels,
                                                        code, forced, partials);
    k4_final <<<1, 1024, 0, stream>>>(partials, out);
}

// Round 2
// 132.174 us; speedup vs baseline: 1.0752x; 1.0752x over previous
//
#include <hip/hip_runtime.h>
#include <stdint.h>
#include <math.h>

#define A_N 65536
#define B_N 16
#define T_N 64
#define NB  (A_N / 256)      // k1 blocks per image = 256
#define EPSF 1e-6f
#define THR_CAND 0.25f       // power of two: 0.25*ue is exact

// ---------------------------------------------------------------------------
// Workspace layout:
//   keys        : B * NB * 64 * u64  = 2 MiB   (per-block best candidate key per target)
//   code        : B * A * u8         = 1 MiB   (best_target_idx | thr<<7)
//   winners     : B * 64 * u32       = 4 KiB
//   fbflag      : B * 64 * u32       = 4 KiB   (1 = target had no candidate)
//   partials    : B * NB * 4 * f32   = 64 KiB  (loss partials with pos:=thr)
//   corrections : B * 4 * f32        = 256 B   (forced-only anchor patches)
// ---------------------------------------------------------------------------

// K1: fused IoU sweep + per-anchor argmax/threshold + candidate emission
//     + full loss terms under pos:=thr assumption.
__global__ __launch_bounds__(256) void k1_main(
    const float4* __restrict__ anchors,
    const float4* __restrict__ bbox,
    const float*  __restrict__ conf,
    const float4* __restrict__ cls,       // 20 floats/anchor = 5 x float4
    const float4* __restrict__ tboxes,
    const int*    __restrict__ tlabels,
    unsigned long long* __restrict__ keys,
    unsigned char* __restrict__ code,
    float* __restrict__ partials)
{
    __shared__ float4 tb[T_N];
    __shared__ float  ta[T_N];
    __shared__ int    tl[T_N];
    __shared__ unsigned long long slot[T_N];
    const int b   = blockIdx.y;
    const int tid = threadIdx.x;
    if (tid < T_N) {
        float4 t = tboxes[b * T_N + tid];
        tb[tid] = t;
        ta[tid] = (t.z - t.x) * (t.w - t.y);
        tl[tid] = tlabels[b * T_N + tid];
        slot[tid] = 0ull;
    }
    __syncthreads();

    const int a = blockIdx.x * 256 + tid;
    const float4 an = anchors[a];
    const float a1 = (an.z - an.x) * (an.w - an.y);
    const unsigned int lo = ~(unsigned int)a;   // smaller idx -> larger lo (first-max ties)

    // peel s=0 so the best-tracker starts valid (matches np first-max semantics)
    float b_inter, b_ue; int b_t = 0;
    {
        const float4 tbx = tb[0];
        float x1 = fmaxf(an.x, tbx.x), y1 = fmaxf(an.y, tbx.y);
        float x2 = fminf(an.z, tbx.z), y2 = fminf(an.w, tbx.w);
        float inter = fmaxf(x2 - x1, 0.f) * fmaxf(y2 - y1, 0.f);
        float u  = a1 + ta[0] - inter;
        float ue = u + EPSF;
        b_inter = inter; b_ue = ue;
        if (inter >= THR_CAND * ue) {
            float iou = inter / ue;
            unsigned long long key =
                ((unsigned long long)__float_as_uint(iou) << 32) | (unsigned long long)lo;
            atomicMax(&slot[0], key);
        }
    }

    #pragma unroll 4
    for (int s = 1; s < 64; ++s) {
        const float4 tbx = tb[s];
        const float  ta_s = ta[s];
        float x1 = fmaxf(an.x, tbx.x), y1 = fmaxf(an.y, tbx.y);
        float x2 = fminf(an.z, tbx.z), y2 = fminf(an.w, tbx.w);
        float inter = fmaxf(x2 - x1, 0.f) * fmaxf(y2 - y1, 0.f);
        float u  = a1 + ta_s - inter;
        float ue = u + EPSF;
        // per-anchor argmax: strictly-greater in ascending s == first-max
        float c1 = inter * b_ue;
        float c2 = b_inter * ue;
        if (c1 > c2) { b_inter = inter; b_ue = ue; b_t = s; }
        // candidate: exact q >= 0.25 (0.25*ue exact)
        if (inter >= THR_CAND * ue) {
            float iou = inter / ue;     // IEEE-exact, matches np bitwise
            unsigned long long key =
                ((unsigned long long)__float_as_uint(iou) << 32) | (unsigned long long)lo;
            atomicMax(&slot[s], key);
        }
    }

    const bool thr = (b_inter >= 0.5f * b_ue);   // max_iou >= POS_THR
    const size_t ba = (size_t)b * A_N + a;
    code[ba] = (unsigned char)(b_t | (thr ? 128 : 0));

    // losses with ct := thr
    const float p  = conf[ba];
    const float w  = thr ? (1.f - p) : p;
    const float fw = w * sqrtf(w);                               // w^1.5
    const float bce = thr ? -logf(p + EPSF) : -logf(1.f - p + EPSF);
    const float cterm = bce * fw * 0.5f;                         // alpha factor == 0.5

    float bterm = 0.f, clterm = 0.f;
    if (thr) {
        const float4 pb = bbox[ba];
        const float4 mb = tb[b_t];
        float x1 = fmaxf(pb.x, mb.x), y1 = fmaxf(pb.y, mb.y);
        float x2 = fminf(pb.z, mb.z), y2 = fminf(pb.w, mb.w);
        float inter = fmaxf(x2 - x1, 0.f) * fmaxf(y2 - y1, 0.f);
        float pa1 = (pb.z - pb.x) * (pb.w - pb.y);
        float pa2 = (mb.z - mb.x) * (mb.w - mb.y);
        float uni = pa1 + pa2 - inter;
        float iou = inter / (uni + EPSF);
        float ex1 = fminf(pb.x, mb.x), ey1 = fminf(pb.y, mb.y);
        float ex2 = fmaxf(pb.z, mb.z), ey2 = fmaxf(pb.w, mb.w);
        float enc = (ex2 - ex1) * (ey2 - ey1);
        float giou = iou - (enc - uni) / (enc + EPSF);
        float gl = 1.f - giou;
        float l1 = 0.25f * (fabsf(pb.x - mb.x) + fabsf(pb.y - mb.y) +
                            fabsf(pb.z - mb.z) + fabsf(pb.w - mb.w));
        bterm = gl + 0.5f * l1;

        const int lab = tl[b_t] - 1;                // 0..19
        const float4* cp = cls + ba * 5;
        float s2 = 0.f, xl = 0.f;
        #pragma unroll
        for (int q = 0; q < 5; ++q) {
            float4 v = cp[q];
            float xs[4] = {v.x, v.y, v.z, v.w};
            #pragma unroll
            for (int j = 0; j < 4; ++j) {
                float x = xs[j];
                s2 += fmaxf(x, 0.f) + log1pf(expf(-fabsf(x)));
                if (q * 4 + j == lab) xl = x;
            }
        }
        clterm = (s2 - xl) * (1.f / 20.f);
    }

    // block reduction of {cterm, ct, bterm, clterm}
    float r0 = cterm, r1 = thr ? 1.f : 0.f, r2 = bterm, r3 = clterm;
    #pragma unroll
    for (int off = 32; off; off >>= 1) {
        r0 += __shfl_down(r0, off, 64);
        r1 += __shfl_down(r1, off, 64);
        r2 += __shfl_down(r2, off, 64);
        r3 += __shfl_down(r3, off, 64);
    }
    __shared__ float red[4][4];
    const int wv = tid >> 6;
    if ((tid & 63) == 0) { red[wv][0] = r0; red[wv][1] = r1; red[wv][2] = r2; red[wv][3] = r3; }
    __syncthreads();
    if (tid < 4) {
        float v = red[0][tid] + red[1][tid] + red[2][tid] + red[3][tid];
        partials[(((size_t)b * NB) + blockIdx.x) * 4 + tid] = v;
    }
    if (tid < T_N)
        keys[(((size_t)b * NB + blockIdx.x) << 6) | tid] = slot[tid];
}

// K2: reduce per-block keys -> winner anchor per (image, target); flag empties.
__global__ __launch_bounds__(1024) void k2_reduce(
    const unsigned long long* __restrict__ keys,
    unsigned int* __restrict__ winners,
    unsigned int* __restrict__ fbflag)
{
    const int b   = blockIdx.x;
    const int tid = threadIdx.x;
    const int t   = tid & 63;
    const int g   = tid >> 6;     // 0..15
    unsigned long long K = 0ull;
    #pragma unroll
    for (int i = 0; i < 4; ++i) {
        unsigned long long k0 = keys[(((size_t)b * NB + (g + 16 * (4 * i + 0))) << 6) | t];
        unsigned long long k1 = keys[(((size_t)b * NB + (g + 16 * (4 * i + 1))) << 6) | t];
        unsigned long long k2 = keys[(((size_t)b * NB + (g + 16 * (4 * i + 2))) << 6) | t];
        unsigned long long k3 = keys[(((size_t)b * NB + (g + 16 * (4 * i + 3))) << 6) | t];
        if (k0 > K) K = k0;
        if (k1 > K) K = k1;
        if (k2 > K) K = k2;
        if (k3 > K) K = k3;
    }
    __shared__ unsigned long long sh[16][64];
    sh[g][t] = K;
    __syncthreads();
    if (tid < 64) {
        unsigned long long m = sh[0][tid];
        #pragma unroll
        for (int g2 = 1; g2 < 16; ++g2) {
            unsigned long long k = sh[g2][tid];
            if (k > m) m = k;
        }
        winners[b * 64 + tid] = (m == 0ull) ? 0xFFFFFFFFu
                                            : ~(unsigned int)(m & 0xFFFFFFFFull);
        fbflag[b * 64 + tid]  = (m == 0ull) ? 1u : 0u;
    }
}

// K2b: exact fallback for targets with no candidate (normally exits instantly).
__global__ __launch_bounds__(256) void k2b_fallback(
    const float4* __restrict__ anchors,
    const float4* __restrict__ tboxes,
    const unsigned int* __restrict__ fbflag,
    unsigned int* __restrict__ winners)
{
    const int t = blockIdx.x, b = blockIdx.y;
    if (fbflag[b * 64 + t] == 0u) return;
    const int tid = threadIdx.x;
    const float4 tbx = tboxes[b * 64 + t];
    const float a2 = (tbx.z - tbx.x) * (tbx.w - tbx.y);
    unsigned long long K = 0ull;
    for (int i = tid; i < A_N; i += 256) {
        float4 an = anchors[i];
        float x1 = fmaxf(an.x, tbx.x), y1 = fmaxf(an.y, tbx.y);
        float x2 = fminf(an.z, tbx.z), y2 = fminf(an.w, tbx.w);
        float inter = fmaxf(x2 - x1, 0.f) * fmaxf(y2 - y1, 0.f);
        float a1 = (an.z - an.x) * (an.w - an.y);
        float u  = a1 + a2 - inter;
        float ue = u + EPSF;
        float iou = inter / ue;
        unsigned long long key =
            ((unsigned long long)__float_as_uint(iou) << 32) |
            (unsigned long long)(~(unsigned int)i);
        if (key > K) K = key;
    }
    #pragma unroll
    for (int off = 32; off; off >>= 1) {
        unsigned long long o = __shfl_down(K, off, 64);
        if (o > K) K = o;
    }
    __shared__ unsigned long long sw[4];
    if ((tid & 63) == 0) sw[tid >> 6] = K;
    __syncthreads();
    if (tid == 0) {
        #pragma unroll
        for (int i2 = 1; i2 < 4; ++i2) if (sw[i2] > K) K = sw[i2];
        winners[b * 64 + t] = ~(unsigned int)(K & 0xFFFFFFFFull);
    }
}

// K3c: per-image corrections for forced-only anchors (winner & !thr), deduped.
__global__ __launch_bounds__(64) void k3c_corr(
    const float4* __restrict__ bbox,
    const float*  __restrict__ conf,
    const float4* __restrict__ cls,
    const float4* __restrict__ tboxes,
    const int*    __restrict__ tlabels,
    const unsigned int* __restrict__ winners,
    const unsigned char* __restrict__ code,
    float* __restrict__ corrections)
{
    const int b = blockIdx.x, lane = threadIdx.x;
    const unsigned int wa = winners[b * 64 + lane];
    bool owner = true;
    for (int k = 0; k < 64; ++k) {
        unsigned int o = __shfl(wa, k, 64);
        if (k < lane && o == wa) owner = false;
    }
    const size_t ba = (size_t)b * A_N + wa;
    const unsigned char c = code[ba];
    float d0 = 0.f, d1 = 0.f, d2 = 0.f, d3 = 0.f;
    if (owner && (c & 128) == 0) {
        const float p = conf[ba];
        float w1 = 1.f - p;
        float f1 = -logf(p + EPSF)       * (w1 * sqrtf(w1)) * 0.5f;   // f(p, ct=1)
        float f0 = -logf(1.f - p + EPSF) * (p  * sqrtf(p))  * 0.5f;   // f(p, ct=0)
        d0 = f1 - f0;
        d1 = 1.f;
        const int bt = c & 63;
        const float4 pb = bbox[ba];
        const float4 mb = tboxes[b * 64 + bt];
        float x1 = fmaxf(pb.x, mb.x), y1 = fmaxf(pb.y, mb.y);
        float x2 = fminf(pb.z, mb.z), y2 = fminf(pb.w, mb.w);
        float inter = fmaxf(x2 - x1, 0.f) * fmaxf(y2 - y1, 0.f);
        float pa1 = (pb.z - pb.x) * (pb.w - pb.y);
        float pa2 = (mb.z - mb.x) * (mb.w - mb.y);
        float uni = pa1 + pa2 - inter;
        float iou = inter / (uni + EPSF);
        float ex1 = fminf(pb.x, mb.x), ey1 = fminf(pb.y, mb.y);
        float ex2 = fmaxf(pb.z, mb.z), ey2 = fmaxf(pb.w, mb.w);
        float enc = (ex2 - ex1) * (ey2 - ey1);
        float giou = iou - (enc - uni) / (enc + EPSF);
        float gl = 1.f - giou;
        float l1 = 0.25f * (fabsf(pb.x - mb.x) + fabsf(pb.y - mb.y) +
                            fabsf(pb.z - mb.z) + fabsf(pb.w - mb.w));
        d2 = gl + 0.5f * l1;

        const int lab = tlabels[b * 64 + bt] - 1;
        const float4* cp = cls + ba * 5;
        float s2 = 0.f, xl = 0.f;
        #pragma unroll
        for (int q = 0; q < 5; ++q) {
            float4 v = cp[q];
            float xs[4] = {v.x, v.y, v.z, v.w};
            #pragma unroll
            for (int j = 0; j < 4; ++j) {
                float x = xs[j];
                s2 += fmaxf(x, 0.f) + log1pf(expf(-fabsf(x)));
                if (q * 4 + j == lab) xl = x;
            }
        }
        d3 = (s2 - xl) * (1.f / 20.f);
    }
    #pragma unroll
    for (int off = 32; off; off >>= 1) {
        d0 += __shfl_down(d0, off, 64);
        d1 += __shfl_down(d1, off, 64);
        d2 += __shfl_down(d2, off, 64);
        d3 += __shfl_down(d3, off, 64);
    }
    if (lane == 0) {
        corrections[b * 4 + 0] = d0;
        corrections[b * 4 + 1] = d1;
        corrections[b * 4 + 2] = d2;
        corrections[b * 4 + 3] = d3;
    }
}

// K4: final per-image losses and batch means -> 4 outputs.
__global__ __launch_bounds__(1024) void k4_final(
    const float* __restrict__ partials,
    const float* __restrict__ corrections,
    float* __restrict__ out)
{
    const int tid  = threadIdx.x;
    const int b    = tid >> 6;
    const int lane = tid & 63;
    float s0 = 0.f, s1 = 0.f, s2 = 0.f, s3 = 0.f;
    #pragma unroll
    for (int i = 0; i < 4; ++i) {
        const float* p = partials + (((size_t)b * NB) + (lane + 64 * i)) * 4;
        s0 += p[0]; s1 += p[1]; s2 += p[2]; s3 += p[3];
    }
    #pragma unroll
    for (int off = 32; off; off >>= 1) {
        s0 += __shfl_down(s0, off, 64);
        s1 += __shfl_down(s1, off, 64);
        s2 += __shfl_down(s2, off, 64);
        s3 += __shfl_down(s3, off, 64);
    }
    __shared__ float L[16][3];
    if (lane == 0) {
        s0 += corrections[b * 4 + 0];
        s1 += corrections[b * 4 + 1];
        s2 += corrections[b * 4 + 2];
        s3 += corrections[b * 4 + 3];
        float confL = s0 / (float)A_N;
        float npos  = fmaxf(s1, 1.f);
        L[b][0] = confL;
        L[b][1] = s2 / npos;
        L[b][2] = s3 / npos;
    }
    __syncthreads();
    if (tid == 0) {
        float cm = 0.f, bm = 0.f, lm = 0.f;
        #pragma unroll
        for (int i = 0; i < 16; ++i) { cm += L[i][0]; bm += L[i][1]; lm += L[i][2]; }
        cm *= (1.f / 16.f); bm *= (1.f / 16.f); lm *= (1.f / 16.f);
        out[0] = cm + bm + lm;
        out[1] = cm;
        out[2] = bm;
        out[3] = lm;
    }
}

extern "C" void kernel_launch(void* const* d_in, const int* in_sizes, int n_in,
                              void* d_out, int out_size, void* d_ws, size_t ws_size,
                              hipStream_t stream)
{
    const float4* bbox    = (const float4*)d_in[0];
    const float*  conf    = (const float*) d_in[1];
    const float4* cls     = (const float4*)d_in[2];
    const float4* anchors = (const float4*)d_in[3];
    const float4* tboxes  = (const float4*)d_in[4];
    const int*    tlabels = (const int*)   d_in[5];
    float* out = (float*)d_out;

    char* ws = (char*)d_ws;
    unsigned long long* keys     = (unsigned long long*)ws;                 // 2 MiB
    unsigned char*      code     = (unsigned char*)(ws + (2u << 20));       // 1 MiB
    unsigned int*       winners  = (unsigned int*)(ws + (3u << 20));        // 4 KiB
    unsigned int*       fbflag   = (unsigned int*)(ws + (3u << 20) + 4096); // 4 KiB
    float*              partials = (float*)(ws + (3u << 20) + 8192);        // 64 KiB
    float*              corrections = (float*)(ws + (3u << 20) + 8192 + 65536); // 256 B

    k1_main     <<<dim3(NB, B_N), 256, 0, stream>>>(anchors, bbox, conf, cls, tboxes,
                                                    tlabels, keys, code, partials);
    k2_reduce   <<<B_N, 1024, 0, stream>>>(keys, winners, fbflag);
    k2b_fallback<<<dim3(T_N, B_N), 256, 0, stream>>>(anchors, tboxes, fbflag, winners);
    k3c_corr    <<<B_N, 64, 0, stream>>>(bbox, conf, cls, tboxes, tlabels,
                                         winners, code, corrections);
    k4_final    <<<1, 1024, 0, stream>>>(partials, corrections, out);
}